// Round 4
// baseline (178.115 us; speedup 1.0000x reference)
//
#include <hip/hip_runtime.h>

// B=32, H=W=128, C_IN=C_OUT=32, 3x3 SAME conv, per-sample hypernet weights
// Wk[b] = (P[b] @ dense_w).reshape(3,3,32,32).
//
// R9: direct-f32 conv, no X staging.
//  R8 post-mortem: VGPR_Count=108 proves the compiler SANK the g1 register
//  prefetch (needed 136+ regs under a 128 cap) -> pipeline never existed;
//  128KB LDS pinned 1 block/CU (8 waves). Root insight: X reuse factor is
//  only 3 (rows) and is L1/L2-served when blocks are XCD-local -> LDS
//  staging is unnecessary. NEW: per-tap f32 global loads + in-reg cvt,
//  1024 blocks x 256 thr (wave = 1 row), launch_bounds(256,3) -> 12
//  waves/CU and a 170-VGPR budget the 2-slot trio pipeline actually fits.
//  Traffic: X 67 (HBM once, taps from cache) + Y 67 + WB slop ~= 140 MB.

#define BATCH 32
#define HDIM 128
#define WDIM 128
#define CIN 32
#define COUT 32
#define PDIM 128
#define KCOLS 9216  // 3*3*32*32

typedef _Float16 f16x8 __attribute__((ext_vector_type(8)));
typedef float f32x4 __attribute__((ext_vector_type(4)));

__device__ __forceinline__ f16x8 zero8() {
    f16x8 z;
#pragma unroll
    for (int j = 0; j < 8; ++j) z[j] = (_Float16)0.f;
    return z;
}

__device__ __forceinline__ f16x8 cvt8(f32x4 lo, f32x4 hi) {
    f16x8 o;
#pragma unroll
    for (int j = 0; j < 4; ++j) {
        o[j] = (_Float16)lo[j];
        o[4 + j] = (_Float16)hi[j];
    }
    return o;
}

// ---------------------------------------------------------------------------
// hyper_gemm: A = P @ dense_w -> f16, swizzled to MFMA B-frag layout
// WB[b][((kc*2 + co>>4)*64 + (ci>>3)*16 + (co&15))*8 + (ci&7)].
// 288 blocks x 256 thr (verified R8). Dw col-panel read twice (L3-served).
// ---------------------------------------------------------------------------
__global__ __launch_bounds__(256) void hyper_gemm(const float* __restrict__ P,
                                                  const float* __restrict__ Dw,
                                                  unsigned short* __restrict__ WB) {
    const int tid = threadIdx.x;
    const int lane = tid & 63;
    const int cg = blockIdx.x % 144;
    const int bq = blockIdx.x / 144;  // 0..1
    const int col = cg * 64 + lane;
    const int b0 = __builtin_amdgcn_readfirstlane(bq * 16 + (tid >> 6) * 4);
    const float* pb = P + (size_t)b0 * PDIM;  // wave-uniform base -> s_load

    float acc[4];
#pragma unroll
    for (int j = 0; j < 4; ++j) acc[j] = 0.f;

#pragma unroll 2
    for (int mm = 0; mm < PDIM; mm += 16) {
        float d[16];
#pragma unroll
        for (int u = 0; u < 16; ++u) d[u] = Dw[(size_t)(mm + u) * KCOLS + col];
#pragma unroll
        for (int u = 0; u < 16; ++u) {
#pragma unroll
            for (int j = 0; j < 4; ++j) acc[j] += d[u] * pb[j * PDIM + mm + u];
        }
    }

    const int co = col & 31;
    const int k = col >> 5;
    const int kc = k >> 5;
    const int ci = k & 31;
    const int base =
        ((kc * 2 + (co >> 4)) * 64 + (ci >> 3) * 16 + (co & 15)) * 8 + (ci & 7);
#pragma unroll
    for (int j = 0; j < 4; ++j) {
        _Float16 v = (_Float16)acc[j];
        WB[(size_t)(b0 + j) * KCOLS + base] = __builtin_bit_cast(unsigned short, v);
    }
}

// ---------------------------------------------------------------------------
// conv_direct: implicit-GEMM conv reading f32 X straight from global.
// Grid 1024 (XCD-swizzled: 4 images/XCD), block = 256 thr / 4 waves, wave =
// one output row (8 tiles of 16 px). Per tile, 3 kh-trios software-pipelined:
// issue next trio's 6 global_load_dwordx4 -> cvt current trio to f16 ->
// 6 MFMA 16x16x32_f16. Row-validity (kh off image) is wave-uniform scalar
// branch; tile-edge lanes zeroed only at t==0/t==7 (R8-verified math).
// B-frags (18 f16x8 = 72 VGPR) hoisted once per wave (global, L2-hot).
// launch_bounds(256,3): 3 blocks/CU resident (12 waves/CU), VGPR cap ~170 so
// the trio pipeline + bf hoist fit WITHOUT load sinking (R8's failure).
// ---------------------------------------------------------------------------

// Load one kw tap (16 px x 8 ci as 2 f32x4) of trio (TT, KH) into slot S.
// rp##KH is the wave-uniform row base; per-lane offset = ww*CIN + q*8.
#define LDKW(S, TT, KH, KW)                                           \
    {                                                                 \
        int ww = (TT) * 16 + m16 + (KW) - 1;                          \
        if ((TT) == 0 && (KW) == 0) ww = ww < 0 ? 0 : ww;             \
        if ((TT) == 7 && (KW) == 2) ww = ww > 127 ? 127 : ww;         \
        const float* p = rp##KH + ww * CIN + qo;                      \
        L[S][KW][0] = *(const f32x4*)p;                               \
        L[S][KW][1] = *(const f32x4*)(p + 4);                         \
    }

#define KHVALID(KH) ((KH) == 0 ? v0 : ((KH) == 2 ? v2 : true))

#define ISSUE(S, TT, KH)                                              \
    if (KHVALID(KH)) {                                                \
        LDKW(S, TT, KH, 0)                                            \
        LDKW(S, TT, KH, 1)                                            \
        LDKW(S, TT, KH, 2)                                            \
    }

#define CONSUME(S, TT, KH)                                                                 \
    {                                                                                      \
        f16x8 a0, a1, a2;                                                                  \
        if (KHVALID(KH)) {                                                                 \
            a0 = cvt8(L[S][0][0], L[S][0][1]);                                             \
            a1 = cvt8(L[S][1][0], L[S][1][1]);                                             \
            a2 = cvt8(L[S][2][0], L[S][2][1]);                                             \
            if ((TT) == 0 && m16 == 0) a0 = zero8();                                       \
            if ((TT) == 7 && m16 == 15) a2 = zero8();                                      \
        } else {                                                                           \
            a0 = zero8(); a1 = zero8(); a2 = zero8();                                      \
        }                                                                                  \
        acc0 = __builtin_amdgcn_mfma_f32_16x16x32_f16(a0, bf[((KH)*3 + 0) * 2], acc0, 0, 0, 0);     \
        acc1 = __builtin_amdgcn_mfma_f32_16x16x32_f16(a0, bf[((KH)*3 + 0) * 2 + 1], acc1, 0, 0, 0); \
        acc0 = __builtin_amdgcn_mfma_f32_16x16x32_f16(a1, bf[((KH)*3 + 1) * 2], acc0, 0, 0, 0);     \
        acc1 = __builtin_amdgcn_mfma_f32_16x16x32_f16(a1, bf[((KH)*3 + 1) * 2 + 1], acc1, 0, 0, 0); \
        acc0 = __builtin_amdgcn_mfma_f32_16x16x32_f16(a2, bf[((KH)*3 + 2) * 2], acc0, 0, 0, 0);     \
        acc1 = __builtin_amdgcn_mfma_f32_16x16x32_f16(a2, bf[((KH)*3 + 2) * 2 + 1], acc1, 0, 0, 0); \
    }

__global__ __launch_bounds__(256, 3) void conv_direct(const float* __restrict__ X,
                                                      const unsigned short* __restrict__ WB,
                                                      float* __restrict__ Y) {
    const int tid = threadIdx.x;

    // XCD-aware swizzle: 1024 % 8 == 0 -> simple bijective form.
    // XCD x owns images 4x..4x+3 entirely (halo/WB L2-local).
    const int wg = blockIdx.x;
    const int id = (wg & 7) * 128 + (wg >> 3);
    const int b = id >> 5;   // image
    const int hg = id & 31;  // 4-row group
    const int wave = tid >> 6;
    const int lane = tid & 63;
    const int q = lane >> 4;    // ci octet
    const int m16 = lane & 15;  // pixel within tile
    const int h = hg * 4 + wave;
    const int qo = q * 8;

    // ---- B-fragments: direct global -> reg (18.4 KB/image, L2-hot) ----
    f16x8 bf[18];
    {
        const f16x8* wbp = (const f16x8*)(WB + (size_t)b * KCOLS);
#pragma unroll
        for (int i = 0; i < 18; ++i) bf[i] = wbp[i * 64 + lane];
    }

    const bool v0 = (h > 0);
    const bool v2 = (h < HDIM - 1);
    const float* xb = X + (size_t)b * HDIM * WDIM * CIN;
    const float* rp0 = xb + (size_t)(v0 ? h - 1 : 0) * WDIM * CIN;
    const float* rp1 = xb + (size_t)h * WDIM * CIN;
    const float* rp2 = xb + (size_t)(v2 ? h + 1 : 0) * WDIM * CIN;

    // 2-slot trio pipeline: slot of step n (= t*3+kh) is n&1 = (t+kh)&1.
    f32x4 L[2][3][2];  // all indices compile-time after full unroll

    float* ybase = Y + (((size_t)b * HDIM + h) * WDIM + q * 4) * COUT + m16;

    ISSUE(0, 0, 0);  // prologue: (t=0, kh=0) -> slot 0

#pragma unroll
    for (int t = 0; t < 8; ++t) {
        f32x4 acc0 = {0.f, 0.f, 0.f, 0.f};
        f32x4 acc1 = {0.f, 0.f, 0.f, 0.f};

        // step 3t (kh=0): issue (t,1), consume (t,0)
        ISSUE(((t + 1) & 1), t, 1);
        CONSUME((t & 1), t, 0);
        // step 3t+1 (kh=1): issue (t,2), consume (t,1)
        ISSUE((t & 1), t, 2);
        CONSUME(((t + 1) & 1), t, 1);
        // step 3t+2 (kh=2): issue (t+1,0), consume (t,2)
        if (t < 7) ISSUE(((t + 1) & 1), (t + 1), 0);
        CONSUME((t & 1), t, 2);

        // D layout: col = lane&15 (co), row = q*4 + r (pixel). Plain stores:
        // acc0+acc1 halves of each 128B line merge in L2.
        float* yp = ybase + t * 16 * COUT;
#pragma unroll
        for (int r = 0; r < 4; ++r) {
            yp[r * COUT] = acc0[r];
            yp[r * COUT + 16] = acc1[r];
        }
    }
}

extern "C" void kernel_launch(void* const* d_in, const int* in_sizes, int n_in,
                              void* d_out, int out_size, void* d_ws, size_t ws_size,
                              hipStream_t stream) {
    const float* X = (const float*)d_in[0];   // [32,128,128,32]
    const float* P = (const float*)d_in[1];   // [32,128]
    const float* Dw = (const float*)d_in[2];  // [128,9216]
    float* Y = (float*)d_out;                 // [32,128,128,32]
    (void)ws_size;

    unsigned short* WB = (unsigned short*)d_ws;  // 589824 B

    hipLaunchKernelGGL(hyper_gemm, dim3(288), dim3(256), 0, stream, P, Dw, WB);
    hipLaunchKernelGGL(conv_direct, dim3(1024), dim3(256), 0, stream, X, WB, Y);
}